// Round 7
// baseline (80.757 us; speedup 1.0000x reference)
//
#include <hip/hip_runtime.h>

#define NORB 13
#define FEAT 107
#define TWO_PI 6.28318530717958647692f
#define NN 3328                 // 256 atoms * 13 orbitals
#define ROWF (NN * 2)           // floats per row
#define R4 (NN / 2)             // 1664 float4 per row
#define EMAX 4096
#define CAP 128                 // per-atom directed-entry bucket capacity
#define MAXS 64                 // max painted column-blocks per atom (LDS slots)

typedef float f4 __attribute__((ext_vector_type(4)));

// Static device scratch (module-load allocated; no hipMalloc, graph-safe).
__device__ int   g_acnt[256];            // directed entries per atom
__device__ int   g_items[256 * CAP];     // per-atom buckets, packed (b<<13|e<<1|dir)
__device__ int   g_ovh[256];             // overflow chain heads (never in practice)
__device__ int   g_ovnxt[2 * EMAX];
__device__ int   g_ovitem[2 * EMAX];
__device__ float g_phases[EMAX * 8];     // [e][k][re,im]

// (p,q) in 13x13 block -> feature index (or -1) + scale.
// Basis l=[0,0,1,1,2], dims [1,1,3,3,5], offsets [0,1,2,5,8].
// Safe for p or q out of range (returns -1).
__device__ __forceinline__ void map_pq(int p, int q, int& idx, float& scl) {
    const int DIMS[5] = {1, 1, 3, 3, 5};
    const int OFFS[5] = {0, 1, 2, 5, 8};
    idx = -1; scl = 0.0f;
    int o = 0;
    #pragma unroll
    for (int i = 0; i < 5; ++i) {
        #pragma unroll
        for (int j = i; j < 5; ++j) {
            int di = DIMS[i], dj = DIMS[j];
            if (p >= OFFS[i] && p < OFFS[i] + di && q >= OFFS[j] && q < OFFS[j] + dj) {
                idx = o + (p - OFFS[i]) * dj + (q - OFFS[j]);
                scl = (i == j) ? 0.5f : 1.0f;
            }
            o += di * dj;
        }
    }
}

// ============================ FAST PATH =====================================

__global__ void init_kernel() {
    int t = threadIdx.x;          // 1 block x 256
    g_acnt[t] = 0;
    g_ovh[t] = -1;
}

__global__ void fill_kernel(const int* __restrict__ eidx, const float* __restrict__ kpt,
                            const float* __restrict__ shf, int E, int K) {
    int tid = blockIdx.x * blockDim.x + threadIdx.x;
    if (tid >= 2 * E) return;
    int e = tid >> 1, dir = tid & 1;
    int ei = eidx[e], ej = eidx[E + e];
    int a = dir ? ej : ei;
    int b = dir ? ei : ej;
    int pk = (b << 13) | (e << 1) | dir;
    int slot = atomicAdd(&g_acnt[a], 1);
    if (slot < CAP) {
        g_items[a * CAP + slot] = pk;
    } else {
        int old = atomicExch(&g_ovh[a], tid);
        g_ovnxt[tid] = old;
        g_ovitem[tid] = pk;
    }
    if (dir == 0) {
        float rx = shf[e * 3 + 0], ry = shf[e * 3 + 1], rz = shf[e * 3 + 2];
        for (int k = 0; k < K; ++k) {
            float th = -TWO_PI * (kpt[k * 3] * rx + kpt[k * 3 + 1] * ry + kpt[k * 3 + 2] * rz);
            float s, c;
            __sincosf(th, &s, &c);
            g_phases[e * 8 + k * 2]     = c;
            g_phases[e * 8 + k * 2 + 1] = s;
        }
    }
}

// One block per (k, atom, half-slab). Paint-compute into LDS first, then
// write painted float4s (D) and stream zeros over the rest (C). D and C
// write disjoint float4 sets -> no ordering hazard.
__global__ __launch_bounds__(256)
void fused3_kernel(const float* __restrict__ hop, const float* __restrict__ ons,
                   float* __restrict__ out) {
    int z = blockIdx.x;                 // 0..2047
    int k = z >> 9;
    int a = (z >> 1) & 255;
    int half = z & 1;
    int rbase = half ? 7 : 0;
    int nrows = half ? 6 : 7;
    int t = threadIdx.x;

    __shared__ int ilist[CAP];
    __shared__ unsigned char present[256];
    __shared__ unsigned char smap[256];
    __shared__ unsigned char sblk[MAXS];
    __shared__ unsigned long long wmask[4];
    __shared__ float2 pblk[MAXS][91];   // [slot][row_in_half*13+q]

    int n = g_acnt[a];
    present[t] = 0;
    __syncthreads();
    int nb = n < CAP ? n : CAP;
    for (int i = t; i < nb; i += 256) {
        int pk = g_items[a * CAP + i];
        ilist[i] = pk;
        present[(pk >> 13) & 255] = 1;
    }
    if (t == 0) present[a] = 1;         // diagonal always painted
    __syncthreads();

    // slot assignment via per-wave ballot + prefix popcount
    unsigned long long m = __ballot(present[t] != 0);
    int w = t >> 6;
    if ((t & 63) == 0) wmask[w] = m;
    __syncthreads();
    int nslots = __popcll(wmask[0]) + __popcll(wmask[1]) +
                 __popcll(wmask[2]) + __popcll(wmask[3]);
    bool fallback = (n > CAP) || (nslots > MAXS);

    if (!fallback) {
        if (present[t]) {
            int pre = 0;
            #pragma unroll
            for (int i = 0; i < 4; ++i) if (i < w) pre += __popcll(wmask[i]);
            pre += __popcll(wmask[w] & ((1ull << (t & 63)) - 1ull));
            smap[t] = (unsigned char)pre;
            sblk[pre] = (unsigned char)t;
        } else {
            smap[t] = 255;
        }
        __syncthreads();

        // zero pblk
        float2* pf = &pblk[0][0];
        for (int i = t; i < nslots * 91; i += 256) pf[i] = make_float2(0.f, 0.f);
        __syncthreads();

        // ---- B: paint-compute (91 lanes = (row_in_half, q)) ----
        if (t < 91) {
            int p = rbase + t / 13, q = t % 13;
            int i0, i1; float s0, s1;
            map_pq(p, q, i0, s0);
            map_pq(q, p, i1, s1);
            {   // onsite (real), slot of diagonal
                const float* f = ons + (long)a * FEAT;
                float v = 0.f;
                if (i0 >= 0) v += s0 * f[i0];
                if (i1 >= 0) v += s1 * f[i1];
                pblk[smap[a]][t].x += v;
            }
            for (int i = 0; i < nb; ++i) {
                int pk = ilist[i];
                int b = (pk >> 13) & 255;
                int e = (pk >> 1) & 4095;
                int dir = pk & 1;
                int s = smap[b];
                float hv = dir ? ((i1 >= 0) ? s1 * hop[(long)e * FEAT + i1] : 0.f)
                               : ((i0 >= 0) ? s0 * hop[(long)e * FEAT + i0] : 0.f);
                float pr = g_phases[e * 8 + k * 2];
                float pi = g_phases[e * 8 + k * 2 + 1];
                float2 v = pblk[s][t];
                v.x += pr * hv;
                v.y += (dir ? -pi : pi) * hv;
                pblk[s][t] = v;
            }
        }
        __syncthreads();

        // ---- D: painted float4 writes (coalesced 128B runs, LDS select) ----
        float4* out4 = (float4*)out;
        int ntask8 = nslots * nrows * 8;
        for (int it0 = t; it0 < ntask8; it0 += 256) {
            int lane = it0 & 7;
            int task = it0 >> 3;
            int s = task % nslots;
            int rr = task / nslots;
            int b = sblk[s];
            int fb = (13 * b) >> 1;
            int fe = (13 * b + 12) >> 1;
            int f = fb + lane;
            if (f > fe) continue;
            int c0 = 2 * f, c1 = c0 + 1;
            float4 v;
            {
                int bc = (unsigned)c0 / 13u;
                int mm = smap[bc];
                if (mm != 255) { float2 pv = pblk[mm][rr * 13 + (c0 - 13 * bc)]; v.x = pv.x; v.y = pv.y; }
                else           { v.x = 0.f; v.y = 0.f; }
            }
            {
                int bc = (unsigned)c1 / 13u;
                int mm = smap[bc];
                if (mm != 255) { float2 pv = pblk[mm][rr * 13 + (c1 - 13 * bc)]; v.z = pv.x; v.w = pv.y; }
                else           { v.z = 0.f; v.w = 0.f; }
            }
            long off4 = (long)(k * NN + a * 13 + rbase + rr) * R4 + f;
            out4[off4] = v;
        }

        // ---- C: gated NT zero stream (skip any float4 with a painted col) ----
        f4 z4 = {0.f, 0.f, 0.f, 0.f};
        for (int rr = 0; rr < nrows; ++rr) {
            long rowb = (long)(k * NN + a * 13 + rbase + rr) * R4;
            for (int f = t; f < R4; f += 256) {
                int b0 = (unsigned)(2 * f) / 13u;
                int b1 = (unsigned)(2 * f + 1) / 13u;
                if (smap[b0] != 255 || smap[b1] != 255) continue;
                __builtin_nontemporal_store(z4, (f4*)((float4*)out + rowb + f));
            }
        }
    } else {
        // rare overflow fallback: full zero + atomic paint (proven pattern)
        f4 z4 = {0.f, 0.f, 0.f, 0.f};
        for (int rr = 0; rr < nrows; ++rr) {
            long rowb = (long)(k * NN + a * 13 + rbase + rr) * R4;
            for (int f = t; f < R4; f += 256)
                __builtin_nontemporal_store(z4, (f4*)((float4*)out + rowb + f));
        }
        __syncthreads();
        int maxt = nrows * 13;
        if (t < maxt) {
            int p = rbase + t / 13, q = t % 13;
            int i0, i1; float s0, s1;
            map_pq(p, q, i0, s0);
            map_pq(q, p, i1, s1);
            {
                const float* f = ons + (long)a * FEAT;
                float v = 0.f;
                if (i0 >= 0) v += s0 * f[i0];
                if (i1 >= 0) v += s1 * f[i1];
                long off = (long)(k * NN + a * 13 + p) * ROWF + (a * 13 + q) * 2;
                atomicAdd(&out[off], v);
            }
            int nbl = n < CAP ? n : CAP;
            for (int i = 0; i < nbl; ++i) {
                int pk = g_items[a * CAP + i];
                int b = (pk >> 13) & 255, e = (pk >> 1) & 4095, dir = pk & 1;
                float hv = dir ? ((i1 >= 0) ? s1 * hop[(long)e * FEAT + i1] : 0.f)
                               : ((i0 >= 0) ? s0 * hop[(long)e * FEAT + i0] : 0.f);
                float pr = g_phases[e * 8 + k * 2];
                float pi = g_phases[e * 8 + k * 2 + 1];
                long off = (long)(k * NN + a * 13 + p) * ROWF + (b * 13 + q) * 2;
                atomicAdd(&out[off], pr * hv);
                atomicAdd(&out[off + 1], (dir ? -pi : pi) * hv);
            }
            for (int it = g_ovh[a]; it >= 0; it = g_ovnxt[it]) {
                int pk = g_ovitem[it];
                int b = (pk >> 13) & 255, e = (pk >> 1) & 4095, dir = pk & 1;
                float hv = dir ? ((i1 >= 0) ? s1 * hop[(long)e * FEAT + i1] : 0.f)
                               : ((i0 >= 0) ? s0 * hop[(long)e * FEAT + i0] : 0.f);
                float pr = g_phases[e * 8 + k * 2];
                float pi = g_phases[e * 8 + k * 2 + 1];
                long off = (long)(k * NN + a * 13 + p) * ROWF + (b * 13 + q) * 2;
                atomicAdd(&out[off], pr * hv);
                atomicAdd(&out[off + 1], (dir ? -pi : pi) * hv);
            }
        }
    }
}

// ============================ FALLBACK PATH (round-2, proven) ================

__global__ void zero_kernel(float4* __restrict__ out, long n4) {
    long i = (long)blockIdx.x * blockDim.x + threadIdx.x;
    long stride = (long)gridDim.x * blockDim.x;
    float4 zz = make_float4(0.f, 0.f, 0.f, 0.f);
    for (; i < n4; i += stride) out[i] = zz;
}

template <int CPX>
__global__ void onsite_kernel(const float* __restrict__ onsite, float* __restrict__ out,
                              int K, long nn) {
    int a = blockIdx.x;
    int t = threadIdx.x;
    if (t >= NORB * NORB) return;
    int p = t / NORB, q = t % NORB;
    int i1, i2; float s1, s2;
    map_pq(p, q, i1, s1);
    map_pq(q, p, i2, s2);
    const float* f = onsite + (long)a * FEAT;
    float v = 0.0f;
    if (i1 >= 0) v += s1 * f[i1];
    if (i2 >= 0) v += s2 * f[i2];
    long row = (long)a * NORB + p;
    long col = (long)a * NORB + q;
    for (int k = 0; k < K; ++k) {
        long off = (((long)k * nn + row) * nn + col) * CPX;
        out[off] = v;
    }
}

template <int CPX>
__global__ void edge_kernel(const float* __restrict__ hop, const float* __restrict__ kpts,
                            const float* __restrict__ shift, const int* __restrict__ eidx,
                            float* __restrict__ out, int E, int K, long nn) {
    int e = blockIdx.x;
    int t = threadIdx.x;
    __shared__ float phc[16], phs[16];
    int ei = eidx[e];
    int ej = eidx[E + e];
    if (t < K && t < 16) {
        float rx = shift[(long)e * 3 + 0];
        float ry = shift[(long)e * 3 + 1];
        float rz = shift[(long)e * 3 + 2];
        float th = -TWO_PI * (kpts[t * 3 + 0] * rx + kpts[t * 3 + 1] * ry + kpts[t * 3 + 2] * rz);
        float s, c;
        __sincosf(th, &s, &c);
        phc[t] = c; phs[t] = s;
    }
    __syncthreads();
    if (t >= NORB * NORB) return;
    int p = t / NORB, q = t % NORB;
    int idx; float scl;
    map_pq(p, q, idx, scl);
    if (idx < 0) return;
    float v = scl * hop[(long)e * FEAT + idx];
    long r1 = (long)ei * NORB + p, c1 = (long)ej * NORB + q;
    long r2 = (long)ej * NORB + q, c2 = (long)ei * NORB + p;
    for (int k = 0; k < K; ++k) {
        float pr = phc[k], pi = phs[k];
        long o1 = (((long)k * nn + r1) * nn + c1) * CPX;
        long o2 = (((long)k * nn + r2) * nn + c2) * CPX;
        atomicAdd(&out[o1], pr * v);
        atomicAdd(&out[o2], pr * v);
        if (CPX == 2) {
            atomicAdd(&out[o1 + 1], pi * v);
            atomicAdd(&out[o2 + 1], -pi * v);
        }
    }
}

// ============================================================================

extern "C" void kernel_launch(void* const* d_in, const int* in_sizes, int n_in,
                              void* d_out, int out_size, void* d_ws, size_t ws_size,
                              hipStream_t stream) {
    const float* hop  = (const float*)d_in[0];
    const float* ons  = (const float*)d_in[1];
    const float* kpt  = (const float*)d_in[2];
    const float* shf  = (const float*)d_in[3];
    const int*   eidx = (const int*)d_in[4];

    int E = in_sizes[0] / FEAT;    // 4096
    int N = in_sizes[1] / FEAT;    // 256
    int K = in_sizes[2] / 3;       // 4
    long nn = (long)N * NORB;      // 3328

    float* out = (float*)d_out;
    long knn2 = (long)K * nn * nn * 2;

    bool fast = (N == 256) && (K == 4) && (E <= EMAX) &&
                ((long)out_size == knn2);

    if (fast) {
        init_kernel<<<1, 256, 0, stream>>>();
        fill_kernel<<<(2 * E + 255) / 256, 256, 0, stream>>>(eidx, kpt, shf, E, K);
        fused3_kernel<<<2048, 256, 0, stream>>>(hop, ons, out);
    } else {
        int cpx = ((long)out_size >= knn2) ? 2 : 1;
        long n4 = (long)out_size / 4;
        zero_kernel<<<2048, 256, 0, stream>>>((float4*)out, n4);
        if (cpx == 2) {
            onsite_kernel<2><<<N, 192, 0, stream>>>(ons, out, K, nn);
            edge_kernel<2><<<E, 192, 0, stream>>>(hop, kpt, shf, eidx, out, E, K, nn);
        } else {
            onsite_kernel<1><<<N, 192, 0, stream>>>(ons, out, K, nn);
            edge_kernel<1><<<E, 192, 0, stream>>>(hop, kpt, shf, eidx, out, E, K, nn);
        }
    }
}

// Round 8
// 79.583 us; speedup vs baseline: 1.0148x; 1.0148x over previous
//
#include <hip/hip_runtime.h>

#define NORB 13
#define FEAT 107
#define TWO_PI 6.28318530717958647692f
#define NN 3328                 // 256 atoms * 13 orbitals
#define ROWF (NN * 2)           // floats per row
#define R4 (NN / 2)             // 1664 float4 per row
#define EMAX 4096
#define CAP 128                 // per-atom directed-entry bucket capacity
#define MAXS 48                 // max painted column-blocks per atom (LDS slots)

// Static device scratch (module-load allocated; no hipMalloc, graph-safe).
__device__ int   g_acnt[256];            // directed entries per atom
__device__ int   g_items[256 * CAP];     // per-atom buckets, packed (b<<13|e<<1|dir)
__device__ int   g_ovh[256];             // overflow chain heads (rare)
__device__ int   g_ovnxt[2 * EMAX];
__device__ int   g_ovitem[2 * EMAX];
__device__ float g_phases[EMAX * 8];     // [e][k][re,im]

// (p,q) in 13x13 block -> feature index (or -1) + scale.
// Basis l=[0,0,1,1,2], dims [1,1,3,3,5], offsets [0,1,2,5,8].
__device__ __forceinline__ void map_pq(int p, int q, int& idx, float& scl) {
    const int DIMS[5] = {1, 1, 3, 3, 5};
    const int OFFS[5] = {0, 1, 2, 5, 8};
    idx = -1; scl = 0.0f;
    int o = 0;
    #pragma unroll
    for (int i = 0; i < 5; ++i) {
        #pragma unroll
        for (int j = i; j < 5; ++j) {
            int di = DIMS[i], dj = DIMS[j];
            if (p >= OFFS[i] && p < OFFS[i] + di && q >= OFFS[j] && q < OFFS[j] + dj) {
                idx = o + (p - OFFS[i]) * dj + (q - OFFS[j]);
                scl = (i == j) ? 0.5f : 1.0f;
            }
            o += di * dj;
        }
    }
}

// ============================ FAST PATH =====================================

__global__ void init_kernel() {
    int t = threadIdx.x;          // 1 block x 256
    g_acnt[t] = 0;
    g_ovh[t] = -1;
}

__global__ void fill_kernel(const int* __restrict__ eidx, const float* __restrict__ kpt,
                            const float* __restrict__ shf, int E, int K) {
    int tid = blockIdx.x * blockDim.x + threadIdx.x;
    if (tid >= 2 * E) return;
    int e = tid >> 1, dir = tid & 1;
    int ei = eidx[e], ej = eidx[E + e];
    int a = dir ? ej : ei;
    int b = dir ? ei : ej;
    int pk = (b << 13) | (e << 1) | dir;
    int slot = atomicAdd(&g_acnt[a], 1);
    if (slot < CAP) {
        g_items[a * CAP + slot] = pk;
    } else {
        int old = atomicExch(&g_ovh[a], tid);
        g_ovnxt[tid] = old;
        g_ovitem[tid] = pk;
    }
    if (dir == 0) {
        float rx = shf[e * 3 + 0], ry = shf[e * 3 + 1], rz = shf[e * 3 + 2];
        for (int k = 0; k < K; ++k) {
            float th = -TWO_PI * (kpt[k * 3] * rx + kpt[k * 3 + 1] * ry + kpt[k * 3 + 2] * rz);
            float s, c;
            __sincosf(th, &s, &c);
            g_phases[e * 8 + k * 2]     = c;
            g_phases[e * 8 + k * 2 + 1] = s;
        }
    }
}

// One block per (k, atom, half-slab). Paint-compute into LDS first, then
// write painted float4s (D) and stream zeros over the rest (C). D and C
// write disjoint float4 sets -> no ordering hazard. PLAIN stores throughout.
__global__ __launch_bounds__(256)
void fused3_kernel(const float* __restrict__ hop, const float* __restrict__ ons,
                   float* __restrict__ out) {
    int z = blockIdx.x;                 // 0..2047
    int k = z >> 9;
    int a = (z >> 1) & 255;
    int half = z & 1;
    int rbase = half ? 7 : 0;
    int nrows = half ? 6 : 7;
    int t = threadIdx.x;

    __shared__ int ilist[CAP];
    __shared__ unsigned char present[256];
    __shared__ unsigned char smap[256];
    __shared__ unsigned char sblk[MAXS];
    __shared__ unsigned long long wmask[4];
    __shared__ float2 pblk[MAXS][91];   // [slot][row_in_half*13+q]

    int n = g_acnt[a];
    present[t] = 0;
    __syncthreads();
    int nb = n < CAP ? n : CAP;
    for (int i = t; i < nb; i += 256) {
        int pk = g_items[a * CAP + i];
        ilist[i] = pk;
        present[(pk >> 13) & 255] = 1;
    }
    if (t == 0) present[a] = 1;         // diagonal always painted
    __syncthreads();

    // slot assignment via per-wave ballot + prefix popcount
    unsigned long long m = __ballot(present[t] != 0);
    int w = t >> 6;
    if ((t & 63) == 0) wmask[w] = m;
    __syncthreads();
    int nslots = __popcll(wmask[0]) + __popcll(wmask[1]) +
                 __popcll(wmask[2]) + __popcll(wmask[3]);
    bool fallback = (n > CAP) || (nslots > MAXS);

    if (!fallback) {
        if (present[t]) {
            int pre = 0;
            #pragma unroll
            for (int i = 0; i < 4; ++i) if (i < w) pre += __popcll(wmask[i]);
            pre += __popcll(wmask[w] & ((1ull << (t & 63)) - 1ull));
            smap[t] = (unsigned char)pre;
            sblk[pre] = (unsigned char)t;
        } else {
            smap[t] = 255;
        }
        __syncthreads();

        // zero pblk
        float2* pf = &pblk[0][0];
        for (int i = t; i < nslots * 91; i += 256) pf[i] = make_float2(0.f, 0.f);
        __syncthreads();

        // ---- B: paint-compute (91 lanes = (row_in_half, q)) ----
        if (t < 91) {
            int p = rbase + t / 13, q = t % 13;
            int i0, i1; float s0, s1;
            map_pq(p, q, i0, s0);
            map_pq(q, p, i1, s1);
            {   // onsite (real), slot of diagonal
                const float* f = ons + (long)a * FEAT;
                float v = 0.f;
                if (i0 >= 0) v += s0 * f[i0];
                if (i1 >= 0) v += s1 * f[i1];
                pblk[smap[a]][t].x += v;
            }
            for (int i = 0; i < nb; ++i) {
                int pk = ilist[i];
                int b = (pk >> 13) & 255;
                int e = (pk >> 1) & 4095;
                int dir = pk & 1;
                int s = smap[b];
                float hv = dir ? ((i1 >= 0) ? s1 * hop[(long)e * FEAT + i1] : 0.f)
                               : ((i0 >= 0) ? s0 * hop[(long)e * FEAT + i0] : 0.f);
                float pr = g_phases[e * 8 + k * 2];
                float pi = g_phases[e * 8 + k * 2 + 1];
                float2 v = pblk[s][t];
                v.x += pr * hv;
                v.y += (dir ? -pi : pi) * hv;
                pblk[s][t] = v;
            }
        }
        __syncthreads();

        // ---- D: painted float4 writes (coalesced runs, LDS select) ----
        float4* out4 = (float4*)out;
        int ntask8 = nslots * nrows * 8;
        for (int it0 = t; it0 < ntask8; it0 += 256) {
            int lane = it0 & 7;
            int task = it0 >> 3;
            int s = task % nslots;
            int rr = task / nslots;
            int b = sblk[s];
            int fb = (13 * b) >> 1;
            int fe = (13 * b + 12) >> 1;
            int f = fb + lane;
            if (f > fe) continue;
            int c0 = 2 * f, c1 = c0 + 1;
            float4 v;
            {
                int bc = (unsigned)c0 / 13u;
                int mm = smap[bc];
                if (mm != 255) { float2 pv = pblk[mm][rr * 13 + (c0 - 13 * bc)]; v.x = pv.x; v.y = pv.y; }
                else           { v.x = 0.f; v.y = 0.f; }
            }
            {
                int bc = (unsigned)c1 / 13u;
                int mm = smap[bc];
                if (mm != 255) { float2 pv = pblk[mm][rr * 13 + (c1 - 13 * bc)]; v.z = pv.x; v.w = pv.y; }
                else           { v.z = 0.f; v.w = 0.f; }
            }
            long off4 = (long)(k * NN + a * 13 + rbase + rr) * R4 + f;
            out4[off4] = v;
        }

        // ---- C: gated zero stream (skip any float4 with a painted col) ----
        float4 z4 = make_float4(0.f, 0.f, 0.f, 0.f);
        float4* out4c = (float4*)out;
        for (int rr = 0; rr < nrows; ++rr) {
            long rowb = (long)(k * NN + a * 13 + rbase + rr) * R4;
            for (int f = t; f < R4; f += 256) {
                int b0 = (unsigned)(2 * f) / 13u;
                int b1 = (unsigned)(2 * f + 1) / 13u;
                if (smap[b0] != 255 || smap[b1] != 255) continue;
                out4c[rowb + f] = z4;
            }
        }
    } else {
        // rare overflow fallback: full zero + atomic paint (proven pattern)
        float4 z4 = make_float4(0.f, 0.f, 0.f, 0.f);
        float4* out4 = (float4*)out;
        for (int rr = 0; rr < nrows; ++rr) {
            long rowb = (long)(k * NN + a * 13 + rbase + rr) * R4;
            for (int f = t; f < R4; f += 256)
                out4[rowb + f] = z4;
        }
        __syncthreads();
        int maxt = nrows * 13;
        if (t < maxt) {
            int p = rbase + t / 13, q = t % 13;
            int i0, i1; float s0, s1;
            map_pq(p, q, i0, s0);
            map_pq(q, p, i1, s1);
            {
                const float* f = ons + (long)a * FEAT;
                float v = 0.f;
                if (i0 >= 0) v += s0 * f[i0];
                if (i1 >= 0) v += s1 * f[i1];
                long off = (long)(k * NN + a * 13 + p) * ROWF + (a * 13 + q) * 2;
                atomicAdd(&out[off], v);
            }
            int nbl = n < CAP ? n : CAP;
            for (int i = 0; i < nbl; ++i) {
                int pk = g_items[a * CAP + i];
                int b = (pk >> 13) & 255, e = (pk >> 1) & 4095, dir = pk & 1;
                float hv = dir ? ((i1 >= 0) ? s1 * hop[(long)e * FEAT + i1] : 0.f)
                               : ((i0 >= 0) ? s0 * hop[(long)e * FEAT + i0] : 0.f);
                float pr = g_phases[e * 8 + k * 2];
                float pi = g_phases[e * 8 + k * 2 + 1];
                long off = (long)(k * NN + a * 13 + p) * ROWF + (b * 13 + q) * 2;
                atomicAdd(&out[off], pr * hv);
                atomicAdd(&out[off + 1], (dir ? -pi : pi) * hv);
            }
            for (int it = g_ovh[a]; it >= 0; it = g_ovnxt[it]) {
                int pk = g_ovitem[it];
                int b = (pk >> 13) & 255, e = (pk >> 1) & 4095, dir = pk & 1;
                float hv = dir ? ((i1 >= 0) ? s1 * hop[(long)e * FEAT + i1] : 0.f)
                               : ((i0 >= 0) ? s0 * hop[(long)e * FEAT + i0] : 0.f);
                float pr = g_phases[e * 8 + k * 2];
                float pi = g_phases[e * 8 + k * 2 + 1];
                long off = (long)(k * NN + a * 13 + p) * ROWF + (b * 13 + q) * 2;
                atomicAdd(&out[off], pr * hv);
                atomicAdd(&out[off + 1], (dir ? -pi : pi) * hv);
            }
        }
    }
}

// ============================ FALLBACK PATH (round-2, proven) ================

__global__ void zero_kernel(float4* __restrict__ out, long n4) {
    long i = (long)blockIdx.x * blockDim.x + threadIdx.x;
    long stride = (long)gridDim.x * blockDim.x;
    float4 zz = make_float4(0.f, 0.f, 0.f, 0.f);
    for (; i < n4; i += stride) out[i] = zz;
}

template <int CPX>
__global__ void onsite_kernel(const float* __restrict__ onsite, float* __restrict__ out,
                              int K, long nn) {
    int a = blockIdx.x;
    int t = threadIdx.x;
    if (t >= NORB * NORB) return;
    int p = t / NORB, q = t % NORB;
    int i1, i2; float s1, s2;
    map_pq(p, q, i1, s1);
    map_pq(q, p, i2, s2);
    const float* f = onsite + (long)a * FEAT;
    float v = 0.0f;
    if (i1 >= 0) v += s1 * f[i1];
    if (i2 >= 0) v += s2 * f[i2];
    long row = (long)a * NORB + p;
    long col = (long)a * NORB + q;
    for (int k = 0; k < K; ++k) {
        long off = (((long)k * nn + row) * nn + col) * CPX;
        out[off] = v;
    }
}

template <int CPX>
__global__ void edge_kernel(const float* __restrict__ hop, const float* __restrict__ kpts,
                            const float* __restrict__ shift, const int* __restrict__ eidx,
                            float* __restrict__ out, int E, int K, long nn) {
    int e = blockIdx.x;
    int t = threadIdx.x;
    __shared__ float phc[16], phs[16];
    int ei = eidx[e];
    int ej = eidx[E + e];
    if (t < K && t < 16) {
        float rx = shift[(long)e * 3 + 0];
        float ry = shift[(long)e * 3 + 1];
        float rz = shift[(long)e * 3 + 2];
        float th = -TWO_PI * (kpts[t * 3 + 0] * rx + kpts[t * 3 + 1] * ry + kpts[t * 3 + 2] * rz);
        float s, c;
        __sincosf(th, &s, &c);
        phc[t] = c; phs[t] = s;
    }
    __syncthreads();
    if (t >= NORB * NORB) return;
    int p = t / NORB, q = t % NORB;
    int idx; float scl;
    map_pq(p, q, idx, scl);
    if (idx < 0) return;
    float v = scl * hop[(long)e * FEAT + idx];
    long r1 = (long)ei * NORB + p, c1 = (long)ej * NORB + q;
    long r2 = (long)ej * NORB + q, c2 = (long)ei * NORB + p;
    for (int k = 0; k < K; ++k) {
        float pr = phc[k], pi = phs[k];
        long o1 = (((long)k * nn + r1) * nn + c1) * CPX;
        long o2 = (((long)k * nn + r2) * nn + c2) * CPX;
        atomicAdd(&out[o1], pr * v);
        atomicAdd(&out[o2], pr * v);
        if (CPX == 2) {
            atomicAdd(&out[o1 + 1], pi * v);
            atomicAdd(&out[o2 + 1], -pi * v);
        }
    }
}

// ============================================================================

extern "C" void kernel_launch(void* const* d_in, const int* in_sizes, int n_in,
                              void* d_out, int out_size, void* d_ws, size_t ws_size,
                              hipStream_t stream) {
    const float* hop  = (const float*)d_in[0];
    const float* ons  = (const float*)d_in[1];
    const float* kpt  = (const float*)d_in[2];
    const float* shf  = (const float*)d_in[3];
    const int*   eidx = (const int*)d_in[4];

    int E = in_sizes[0] / FEAT;    // 4096
    int N = in_sizes[1] / FEAT;    // 256
    int K = in_sizes[2] / 3;       // 4
    long nn = (long)N * NORB;      // 3328

    float* out = (float*)d_out;
    long knn2 = (long)K * nn * nn * 2;

    bool fast = (N == 256) && (K == 4) && (E <= EMAX) &&
                ((long)out_size == knn2);

    if (fast) {
        init_kernel<<<1, 256, 0, stream>>>();
        fill_kernel<<<(2 * E + 255) / 256, 256, 0, stream>>>(eidx, kpt, shf, E, K);
        fused3_kernel<<<2048, 256, 0, stream>>>(hop, ons, out);
    } else {
        int cpx = ((long)out_size >= knn2) ? 2 : 1;
        long n4 = (long)out_size / 4;
        zero_kernel<<<2048, 256, 0, stream>>>((float4*)out, n4);
        if (cpx == 2) {
            onsite_kernel<2><<<N, 192, 0, stream>>>(ons, out, K, nn);
            edge_kernel<2><<<E, 192, 0, stream>>>(hop, kpt, shf, eidx, out, E, K, nn);
        } else {
            onsite_kernel<1><<<N, 192, 0, stream>>>(ons, out, K, nn);
            edge_kernel<1><<<E, 192, 0, stream>>>(hop, kpt, shf, eidx, out, E, K, nn);
        }
    }
}